// Round 4
// baseline (312.607 us; speedup 1.0000x reference)
//
#include <hip/hip_runtime.h>
#include <math.h>

constexpr int C  = 128;
constexpr int H  = 128;
constexpr int Wd = 128;
constexpr int HW = H * Wd;
constexpr int LH = 64, LW = 64;
constexpr int RW = 130;               // k/v row stride: 2 left-pad zero cols
constexpr int PLANE = H * RW;         // 16640 floats per (n,c) plane
constexpr int KVSZ = 2 * C * PLANE;   // 4,259,840 floats per buffer
constexpr int PARTSZ = 2 * 4 * 2 * HW; // 262,144 floats

// 4-byte-aligned float4 for unaligned vector loads
struct __attribute__((packed, aligned(4))) f4u { float x, y, z, w; };

__device__ __forceinline__ float sel4(const f4u& v, int i) {
  // dynamic extract -> cndmask chain (no scratch)
  return i == 0 ? v.x : (i == 1 ? v.y : (i == 2 ? v.z : v.w));
}

// ---------------------------------------------------------------------------
// Kernel 1 (pre): thread = one (n,c,y, 4-px group). No LDS, no barriers.
//   - hr rows via aligned dwordx4 + 2 clamped scalars -> k,v dwconv
//   - lr bilinear halo (3x6) via 2 f4u per row-pair -> lr_up + q dwconv
//   - k,v stored into left-padded planes (stride 130, cols 0,1 zero)
// grid 4096 blocks x 256.
// ---------------------------------------------------------------------------
__global__ __launch_bounds__(256) void k_pre(
    const float* __restrict__ hr, const float* __restrict__ lr,
    const float* __restrict__ wq, const float* __restrict__ bq,
    const float* __restrict__ wk, const float* __restrict__ bk,
    const float* __restrict__ wv, const float* __restrict__ bv,
    float* __restrict__ lrup_out, float* __restrict__ qout,
    float* __restrict__ kpad, float* __restrict__ vpad,
    float* __restrict__ gap)
{
  const int t  = blockIdx.x * 256 + threadIdx.x;
  const int x4 = t & 31;
  const int y  = (t >> 5) & 127;
  const int nc = t >> 12;              // uniform within a block (16 blk/nc)
  const int x  = x4 * 4;
  const int c  = nc & (C - 1);

  // ---- hr 3x6 halo (zero-padded) ----
  const float* hp = hr + nc * HW;
  float hrow[3][6];
#pragma unroll
  for (int r = 0; r < 3; r++) {
    const int gy = y + r - 1;
    const bool okr = (gy >= 0) && (gy < H);
    const int gyc = min(max(gy, 0), H - 1);
    const float* rp = hp + gyc * Wd;
    const f4u m = *(const f4u*)(rp + x);          // aligned dwordx4
    const float lft = rp[max(x - 1, 0)];
    const float rgt = rp[min(x + 4, Wd - 1)];
    hrow[r][0] = (okr && x > 0) ? lft : 0.f;
    hrow[r][1] = okr ? m.x : 0.f;
    hrow[r][2] = okr ? m.y : 0.f;
    hrow[r][3] = okr ? m.z : 0.f;
    hrow[r][4] = okr ? m.w : 0.f;
    hrow[r][5] = (okr && x + 4 < Wd) ? rgt : 0.f;
  }

  const float* wkc = wk + c * 9;
  const float* wvc = wv + c * 9;
  float ko[4], vo[4];
#pragma unroll
  for (int j = 0; j < 4; j++) { ko[j] = bk[c]; vo[j] = bv[c]; }
#pragma unroll
  for (int r = 0; r < 3; r++)
#pragma unroll
    for (int dj = 0; dj < 3; dj++) {
      const float a = wkc[r * 3 + dj], b = wvc[r * 3 + dj];
#pragma unroll
      for (int j = 0; j < 4; j++) {
        ko[j] += a * hrow[r][j + dj];
        vo[j] += b * hrow[r][j + dj];
      }
    }

  // ---- lr_up 3x6 halo (bilinear align_corners; OOB -> 0) ----
  const float scale = 63.0f / 127.0f;
  const float* lp = lr + nc * (LH * LW);
  float lrv[3][6];
#pragma unroll
  for (int r = 0; r < 3; r++) {
    const int gy = y + r - 1;
    const bool okr = (gy >= 0) && (gy < H);
    const int gyc = min(max(gy, 0), H - 1);
    const float fy = gyc * scale;
    const int y0 = (int)fy;
    const float wy = fy - y0;
    const int y1 = min(y0 + 1, LH - 1);
    const int gx0 = max(x - 1, 0);
    const int xb = min((int)(gx0 * scale), LW - 4);
    const f4u r0 = *(const f4u*)(lp + y0 * LW + xb);
    const f4u r1 = *(const f4u*)(lp + y1 * LW + xb);
#pragma unroll
    for (int j = 0; j < 6; j++) {
      const int gx = x + j - 1;
      const bool okc = (gx >= 0) && (gx < Wd);
      const int gxc = min(max(gx, 0), Wd - 1);
      const float fx = gxc * scale;
      const int x0 = (int)fx;
      const float wx = fx - x0;
      const int i0 = x0 - xb;
      const int i1 = min(x0 + 1, LW - 1) - xb;
      const float p00 = sel4(r0, i0), p01 = sel4(r0, i1);
      const float p10 = sel4(r1, i0), p11 = sel4(r1, i1);
      const float t0 = p00 + (p01 - p00) * wx;
      const float t1 = p10 + (p11 - p10) * wx;
      lrv[r][j] = (okr && okc) ? (t0 + (t1 - t0) * wy) : 0.f;
    }
  }

  const float* wqc = wq + c * 9;
  float qo[4];
#pragma unroll
  for (int j = 0; j < 4; j++) qo[j] = bq[c];
#pragma unroll
  for (int r = 0; r < 3; r++)
#pragma unroll
    for (int dj = 0; dj < 3; dj++) {
      const float a = wqc[r * 3 + dj];
#pragma unroll
      for (int j = 0; j < 4; j++) qo[j] += a * lrv[r][j + dj];
    }

  // ---- stores ----
  *(float4*)(lrup_out + nc * HW + y * Wd + x) =
      make_float4(lrv[1][1], lrv[1][2], lrv[1][3], lrv[1][4]);
  *(float4*)(qout + nc * HW + y * Wd + x) =
      make_float4(qo[0], qo[1], qo[2], qo[3]);
  float* kr = kpad + nc * PLANE + y * RW + 2 + x;
  float* vr = vpad + nc * PLANE + y * RW + 2 + x;
  kr[0] = ko[0]; kr[1] = ko[1]; kr[2] = ko[2]; kr[3] = ko[3];
  vr[0] = vo[0]; vr[1] = vo[1]; vr[2] = vo[2]; vr[3] = vo[3];
  if (x4 == 0) { kr[-2] = 0.f; kr[-1] = 0.f; vr[-2] = 0.f; vr[-1] = 0.f; }
  if (t < 16) gap[t] = 0.f;   // zero tail between vpad and qbuf
}

// ---------------------------------------------------------------------------
// Kernel 2 (gating conv partials): 64 fused channels per block, weights read
// with WAVE-UNIFORM indices (compiler scalarizes -> s_load; zero LDS).
// thread = 1 px; block = 2 rows x 128 px. grid (64, 4, 2) = 512 blocks.
// cs 0,1 -> q half (unpadded buf); cs 2,3 -> k half (padded planes).
// ---------------------------------------------------------------------------
__global__ __launch_bounds__(256) void k_dyn(
    const float* __restrict__ qb, const float* __restrict__ kpad,
    const float* __restrict__ wa, float* __restrict__ part)
{
  const int x = threadIdx.x & 127;
  const int y = blockIdx.x * 2 + (threadIdx.x >> 7);
  const int cs = blockIdx.y;
  const int n  = blockIdx.z;
  const bool isQ = (cs < 2);
  const int cb = (cs & 1) * 64;
  float a0 = 0.f, a1 = 0.f;

  for (int i = 0; i < 64; i++) {
    const int c = cb + i;
    float t3[3][3];
    if (isQ) {
      const float* qp = qb + (n * C + c) * HW + y * Wd + x;
#pragma unroll
      for (int r = 0; r < 3; r++) {
        const int gy = y + r - 1;
        if (gy >= 0 && gy < H) {
          const f4u a = *(const f4u*)(qp + (r - 1) * Wd - 1);
          t3[r][0] = (x > 0) ? a.x : 0.f;
          t3[r][1] = a.y;
          t3[r][2] = (x < Wd - 1) ? a.z : 0.f;
        } else { t3[r][0] = t3[r][1] = t3[r][2] = 0.f; }
      }
    } else {
      const float* kp = kpad + (n * C + c) * PLANE + y * RW + 2 + x;
#pragma unroll
      for (int r = 0; r < 3; r++) {
        const int gy = y + r - 1;
        if (gy >= 0 && gy < H) {
          const f4u a = *(const f4u*)(kp + (r - 1) * RW - 1);
          t3[r][0] = a.x; t3[r][1] = a.y; t3[r][2] = a.z;  // pads give zeros
        } else { t3[r][0] = t3[r][1] = t3[r][2] = 0.f; }
      }
    }
    const int fc = isQ ? c : (C + c);
    const float* w0 = wa + fc * 9;           // uniform -> s_load
    const float* w1 = wa + 2304 + fc * 9;
#pragma unroll
    for (int r = 0; r < 3; r++)
#pragma unroll
      for (int dj = 0; dj < 3; dj++) {
        a0 += w0[r * 3 + dj] * t3[r][dj];
        a1 += w1[r * 3 + dj] * t3[r][dj];
      }
  }
  const int p = y * Wd + x;
  part[((n * 4 + cs) * 2 + 0) * HW + p] = a0;
  part[((n * 4 + cs) * 2 + 1) * HW + p] = a1;
}

// ---------------------------------------------------------------------------
// Kernel 3 (attention): Round-1 proven skeleton (LDS reduce, 0 conflicts),
// window rows now 2 loads (f4u + scalar) from padded planes, no masks.
// Block = 32 px x 8 channel-groups (16 ch). grid (4,128,2) = 1024 blocks.
// ---------------------------------------------------------------------------
__global__ __launch_bounds__(256) void k_attn(
    const float* __restrict__ q, const float* __restrict__ kpad,
    const float* __restrict__ vpad, const float* __restrict__ part,
    const float* __restrict__ ba, float* __restrict__ outb)
{
  __shared__ float red[25 * 256];
  __shared__ float dsh[2][32];

  const int tid = threadIdx.x;
  const int px = tid & 31, cg = tid >> 5;
  const int x = blockIdx.x * 32 + px;
  const int y = blockIdx.y;
  const int n = blockIdx.z;
  const int p = y * Wd + x;

  if (tid < 64) {   // finish gating: sum 4 partials + bias, sigmoid
    const int o = tid >> 5, lx = tid & 31;
    const int pp = y * Wd + blockIdx.x * 32 + lx;
    float s = ba[o];
#pragma unroll
    for (int cs = 0; cs < 4; cs++)
      s += part[((n * 4 + cs) * 2 + o) * HW + pp];
    dsh[o][lx] = 1.f / (1.f + expf(-s));
  }

  float sim[25];
#pragma unroll
  for (int k = 0; k < 25; k++) sim[k] = 0.f;

  const int cb = n * C + cg * 16;
  const float* qp = q + cb * HW + p;
  const float* kp = kpad + cb * PLANE + y * RW + x;   // padded col x = tap dx-2
  for (int ci = 0; ci < 16; ci++) {
    const float qv = qp[ci * HW];
    const float* kpp = kp + ci * PLANE;
#pragma unroll
    for (int r = 0; r < 5; r++) {
      const int gy = y + r - 2;
      if (gy >= 0 && gy < H) {          // wave-uniform predicate
        const f4u a = *(const f4u*)(kpp + (r - 2) * RW);
        const float b5 = kpp[(r - 2) * RW + 4];
        sim[r * 5 + 0] += qv * a.x;
        sim[r * 5 + 1] += qv * a.y;
        sim[r * 5 + 2] += qv * a.z;
        sim[r * 5 + 3] += qv * a.w;
        sim[r * 5 + 4] += qv * b5;
      }
    }
  }

#pragma unroll
  for (int k = 0; k < 25; k++) red[k * 256 + tid] = sim[k];
  __syncthreads();

  for (int k = cg; k < 25; k += 8) {
    float s = 0.f;
#pragma unroll
    for (int g = 0; g < 8; g++) s += red[k * 256 + g * 32 + px];
    red[k * 256 + px] = s;
  }
  __syncthreads();

  if (tid < 32) {
    float sv[25], m = -1e30f;
#pragma unroll
    for (int k = 0; k < 25; k++) { sv[k] = red[k * 256 + tid]; m = fmaxf(m, sv[k]); }
    float tot = 0.f;
#pragma unroll
    for (int k = 0; k < 25; k++) { const float e = expf(sv[k] - m); sv[k] = e; tot += e; }
    const float inv = 1.f / tot;
#pragma unroll
    for (int k = 0; k < 25; k++) red[k * 256 + tid] = sv[k] * inv;
  }
  __syncthreads();

  float w[25];
#pragma unroll
  for (int k = 0; k < 25; k++) w[k] = red[k * 256 + px];
  const float d0 = dsh[0][px], d1 = dsh[1][px];

  const float* vp = vpad + cb * PLANE + y * RW + x;
  float* op = outb + cb * HW + p;
  for (int ci = 0; ci < 16; ci++) {
    const float* vpp = vp + ci * PLANE;
    float acc = 0.f, vc = 0.f;
#pragma unroll
    for (int r = 0; r < 5; r++) {
      const int gy = y + r - 2;
      if (gy >= 0 && gy < H) {
        const f4u a = *(const f4u*)(vpp + (r - 2) * RW);
        const float b5 = vpp[(r - 2) * RW + 4];
        acc += w[r * 5 + 0] * a.x + w[r * 5 + 1] * a.y + w[r * 5 + 2] * a.z +
               w[r * 5 + 3] * a.w + w[r * 5 + 4] * b5;
        if (r == 2) vc = a.z;           // center tap (dx=0)
      }
    }
    op[ci * HW] = op[ci * HW] + d0 * acc + d1 * vc;   // op holds lr_up
  }
}

// ---------------------------------------------------------------------------
extern "C" void kernel_launch(void* const* d_in, const int* in_sizes, int n_in,
                              void* d_out, int out_size, void* d_ws,
                              size_t ws_size, hipStream_t stream)
{
  const float* hr = (const float*)d_in[0];
  const float* lr = (const float*)d_in[1];
  const float* wq = (const float*)d_in[2];
  const float* bq = (const float*)d_in[3];
  const float* wk = (const float*)d_in[4];
  const float* bk = (const float*)d_in[5];
  const float* wv = (const float*)d_in[6];
  const float* bv = (const float*)d_in[7];
  const float* wa = (const float*)d_in[8];
  const float* ba = (const float*)d_in[9];

  float* out = (float*)d_out;
  float* ws  = (float*)d_ws;

  // layout: part | kpad | vpad | gap(16) | qbuf  = 49.50 MiB (< proven 50)
  float* partb = ws;
  float* kpad  = partb + PARTSZ;
  float* vpad  = kpad + KVSZ;
  float* gapb  = vpad + KVSZ;
  float* qb    = gapb + 16;

  k_pre<<<dim3(4096), dim3(256), 0, stream>>>(
      hr, lr, wq, bq, wk, bk, wv, bv, out, qb, kpad, vpad, gapb);
  k_dyn<<<dim3(64, 4, 2), dim3(256), 0, stream>>>(qb, kpad, wa, partb);
  k_attn<<<dim3(4, 128, 2), dim3(256), 0, stream>>>(
      qb, kpad, vpad, partb, ba, out);
}

// Round 5
// 192.317 us; speedup vs baseline: 1.6255x; 1.6255x over previous
//
#include <hip/hip_runtime.h>
#include <math.h>

constexpr int C  = 128;
constexpr int H  = 128;
constexpr int Wd = 128;
constexpr int HW = H * Wd;
constexpr int LH = 64, LW = 64;

constexpr int KRW = 130;                // k/v row stride: 2 left-pad zero cols
constexpr int KROWS = 132;              // 2 top + 128 data + 2 bottom zero rows
constexpr int KPLANE = KROWS * KRW;     // 17160
constexpr int QRW = 129;                // q row stride: 1 left-pad zero col
constexpr int QROWS = 130;              // 1 top + 128 + 1 bottom zero rows
constexpr int QPLANE = QROWS * QRW;     // 16770
constexpr int KSZ = 2 * C * KPLANE;     // 4,392,960 floats
constexpr int QSZ = 2 * C * QPLANE;     // 4,293,120 floats
// ws total: 2*KSZ + QSZ + 4 = 13,079,044 floats = 52.32 MB (< proven 50 MiB)

struct __attribute__((packed, aligned(4))) f4u { float x, y, z, w; };

__device__ __forceinline__ float sel4(const f4u& v, int i) {
  return i == 0 ? v.x : (i == 1 ? v.y : (i == 2 ? v.z : v.w));
}

// ---------------------------------------------------------------------------
// Kernel 1 (pre): thread = one (n,c,y, 4-px group). No LDS, no barriers,
// branch-free math (clamped loads + cndmask). Writes lr_up (d_out), q into
// 129-stride padded planes, k/v into 130-stride padded planes; edge threads
// also zero the pad rows/cols so downstream loops never need masks.
// ---------------------------------------------------------------------------
__global__ __launch_bounds__(256) void k_pre(
    const float* __restrict__ hr, const float* __restrict__ lr,
    const float* __restrict__ wq, const float* __restrict__ bq,
    const float* __restrict__ wk, const float* __restrict__ bk,
    const float* __restrict__ wv, const float* __restrict__ bv,
    float* __restrict__ lrup_out, float* __restrict__ qpad,
    float* __restrict__ kpad, float* __restrict__ vpad,
    float* __restrict__ gap)
{
  const int t  = blockIdx.x * 256 + threadIdx.x;
  const int x4 = t & 31;
  const int y  = (t >> 5) & 127;
  const int nc = t >> 12;              // uniform within a block (16 blk/nc)
  const int x  = x4 * 4;
  const int c  = nc & (C - 1);

  // ---- hr 3x6 halo (zero-padded) ----
  const float* hp = hr + nc * HW;
  float hrow[3][6];
#pragma unroll
  for (int r = 0; r < 3; r++) {
    const int gy = y + r - 1;
    const bool okr = (gy >= 0) && (gy < H);
    const int gyc = min(max(gy, 0), H - 1);
    const float* rp = hp + gyc * Wd;
    const f4u m = *(const f4u*)(rp + x);
    const float lft = rp[max(x - 1, 0)];
    const float rgt = rp[min(x + 4, Wd - 1)];
    hrow[r][0] = (okr && x > 0) ? lft : 0.f;
    hrow[r][1] = okr ? m.x : 0.f;
    hrow[r][2] = okr ? m.y : 0.f;
    hrow[r][3] = okr ? m.z : 0.f;
    hrow[r][4] = okr ? m.w : 0.f;
    hrow[r][5] = (okr && x + 4 < Wd) ? rgt : 0.f;
  }

  const float* wkc = wk + c * 9;
  const float* wvc = wv + c * 9;
  float ko[4], vo[4];
#pragma unroll
  for (int j = 0; j < 4; j++) { ko[j] = bk[c]; vo[j] = bv[c]; }
#pragma unroll
  for (int r = 0; r < 3; r++)
#pragma unroll
    for (int dj = 0; dj < 3; dj++) {
      const float a = wkc[r * 3 + dj], b = wvc[r * 3 + dj];
#pragma unroll
      for (int j = 0; j < 4; j++) {
        ko[j] += a * hrow[r][j + dj];
        vo[j] += b * hrow[r][j + dj];
      }
    }

  // ---- lr_up 3x6 halo (bilinear align_corners; OOB -> 0) ----
  const float scale = 63.0f / 127.0f;
  const float* lp = lr + nc * (LH * LW);
  float lrv[3][6];
#pragma unroll
  for (int r = 0; r < 3; r++) {
    const int gy = y + r - 1;
    const bool okr = (gy >= 0) && (gy < H);
    const int gyc = min(max(gy, 0), H - 1);
    const float fy = gyc * scale;
    const int y0 = (int)fy;
    const float wy = fy - y0;
    const int y1 = min(y0 + 1, LH - 1);
    const int gx0 = max(x - 1, 0);
    const int xb = min((int)(gx0 * scale), LW - 4);
    const f4u r0 = *(const f4u*)(lp + y0 * LW + xb);
    const f4u r1 = *(const f4u*)(lp + y1 * LW + xb);
#pragma unroll
    for (int j = 0; j < 6; j++) {
      const int gx = x + j - 1;
      const bool okc = (gx >= 0) && (gx < Wd);
      const int gxc = min(max(gx, 0), Wd - 1);
      const float fx = gxc * scale;
      const int x0 = (int)fx;
      const float wx = fx - x0;
      const int i0 = x0 - xb;
      const int i1 = min(x0 + 1, LW - 1) - xb;
      const float p00 = sel4(r0, i0), p01 = sel4(r0, i1);
      const float p10 = sel4(r1, i0), p11 = sel4(r1, i1);
      const float t0 = p00 + (p01 - p00) * wx;
      const float t1 = p10 + (p11 - p10) * wx;
      lrv[r][j] = (okr && okc) ? (t0 + (t1 - t0) * wy) : 0.f;
    }
  }

  const float* wqc = wq + c * 9;
  float qo[4];
#pragma unroll
  for (int j = 0; j < 4; j++) qo[j] = bq[c];
#pragma unroll
  for (int r = 0; r < 3; r++)
#pragma unroll
    for (int dj = 0; dj < 3; dj++) {
      const float a = wqc[r * 3 + dj];
#pragma unroll
      for (int j = 0; j < 4; j++) qo[j] += a * lrv[r][j + dj];
    }

  // ---- stores ----
  *(float4*)(lrup_out + nc * HW + y * Wd + x) =
      make_float4(lrv[1][1], lrv[1][2], lrv[1][3], lrv[1][4]);

  float* qr = qpad + nc * QPLANE + (y + 1) * QRW + 1 + x;   // odd offset
  qr[0] = qo[0]; qr[1] = qo[1]; qr[2] = qo[2]; qr[3] = qo[3];

  float* kr = kpad + nc * KPLANE + (y + 2) * KRW + 2 + x;   // 8B aligned
  float* vr = vpad + nc * KPLANE + (y + 2) * KRW + 2 + x;
  *(float2*)(kr) = make_float2(ko[0], ko[1]);
  *(float2*)(kr + 2) = make_float2(ko[2], ko[3]);
  *(float2*)(vr) = make_float2(vo[0], vo[1]);
  *(float2*)(vr + 2) = make_float2(vo[2], vo[3]);

  // ---- pad zeroing (ws is poisoned every call) ----
  if (x4 == 0) {   // left pad cols of this data row
    kr[-2] = 0.f; kr[-1] = 0.f; vr[-2] = 0.f; vr[-1] = 0.f; qr[-1] = 0.f;
  }
  if (y == 0) {    // top pad rows
    float* kz = kpad + nc * KPLANE;
    float* vz = vpad + nc * KPLANE;
    float* qz = qpad + nc * QPLANE;
#pragma unroll
    for (int j = 0; j < 4; j++) {
      kz[2 + x + j] = 0.f;        kz[KRW + 2 + x + j] = 0.f;
      vz[2 + x + j] = 0.f;        vz[KRW + 2 + x + j] = 0.f;
      qz[1 + x + j] = 0.f;
    }
    if (x4 == 0) {
      kz[0] = kz[1] = kz[KRW] = kz[KRW + 1] = 0.f;
      vz[0] = vz[1] = vz[KRW] = vz[KRW + 1] = 0.f;
      qz[0] = 0.f;
    }
  }
  if (y == 127) {  // bottom pad rows
    float* kz = kpad + nc * KPLANE + 130 * KRW;
    float* vz = vpad + nc * KPLANE + 130 * KRW;
    float* qz = qpad + nc * QPLANE + 129 * QRW;
#pragma unroll
    for (int j = 0; j < 4; j++) {
      kz[2 + x + j] = 0.f;        kz[KRW + 2 + x + j] = 0.f;
      vz[2 + x + j] = 0.f;        vz[KRW + 2 + x + j] = 0.f;
      qz[1 + x + j] = 0.f;
    }
    if (x4 == 0) {
      kz[0] = kz[1] = kz[KRW] = kz[KRW + 1] = 0.f;
      vz[0] = vz[1] = vz[KRW] = vz[KRW + 1] = 0.f;
      qz[0] = 0.f;
    }
  }
  if (t == 0) { gap[0] = 0.f; gap[1] = 0.f; gap[2] = 0.f; gap[3] = 0.f; }
}

// ---------------------------------------------------------------------------
// Kernel 2 (attention + gating fused).
// Block 512 = 8 waves; wave = 64 px (one row segment) x 16 channels.
// cg = tid>>6 is wave-uniform (readfirstlane) -> gating weights via s_load.
// All inner loops branch-free & mask-free (fully padded planes):
//   k-pass: per ch 5 f4u + 5 scalar k-loads + 3 f4u q-loads, one batch
//   LDS reduce over 8 waves (2-way bank access = free), softmax + sigmoid
//   v-pass: per ch 5 f4u + 5 scalar, epilogue RMW on d_out (holds lr_up)
// grid (2,128,2) = 512 blocks (2/CU, 16 waves/CU).
// ---------------------------------------------------------------------------
__global__ __launch_bounds__(512) void k_attn(
    const float* __restrict__ qpad, const float* __restrict__ kpad,
    const float* __restrict__ vpad, const float* __restrict__ wa,
    const float* __restrict__ ba, float* __restrict__ outb)
{
  __shared__ float red[25 * 512];   // 51.2 KB
  __shared__ float dsh[2 * 512];    // 4 KB

  const int tid = threadIdx.x;
  const int px = tid & 63;
  const int cgu = __builtin_amdgcn_readfirstlane(tid >> 6);  // wave-uniform
  const int x = blockIdx.x * 64 + px;
  const int y = blockIdx.y;
  const int n = blockIdx.z;
  const int c0 = n * C + cgu * 16;

  const float* kb = kpad + c0 * KPLANE + y * KRW + x;  // plane row y = tap dy-2
  const float* qb = qpad + c0 * QPLANE + y * QRW + x;  // plane row y = tap dy-1

  float sim[25];
#pragma unroll
  for (int k = 0; k < 25; k++) sim[k] = 0.f;
  float d0a = 0.f, d1a = 0.f;

#pragma unroll 4
  for (int ci = 0; ci < 16; ci++) {
    const float* kp = kb + ci * KPLANE;
    const float* qp = qb + ci * QPLANE;

    const f4u q0 = *(const f4u*)(qp);            // dx -1..+2 (use .x,.y,.z)
    const f4u q1 = *(const f4u*)(qp + QRW);
    const f4u q2 = *(const f4u*)(qp + 2 * QRW);

    const f4u a0 = *(const f4u*)(kp);            // dx -2..+1
    const f4u a1 = *(const f4u*)(kp + KRW);
    const f4u a2 = *(const f4u*)(kp + 2 * KRW);
    const f4u a3 = *(const f4u*)(kp + 3 * KRW);
    const f4u a4 = *(const f4u*)(kp + 4 * KRW);
    const float b0 = kp[4];                      // dx +2
    const float b1 = kp[KRW + 4];
    const float b2 = kp[2 * KRW + 4];
    const float b3 = kp[3 * KRW + 4];
    const float b4 = kp[4 * KRW + 4];

    const float qv = q1.y;                       // q center
    sim[0]  += qv * a0.x; sim[1]  += qv * a0.y; sim[2]  += qv * a0.z;
    sim[3]  += qv * a0.w; sim[4]  += qv * b0;
    sim[5]  += qv * a1.x; sim[6]  += qv * a1.y; sim[7]  += qv * a1.z;
    sim[8]  += qv * a1.w; sim[9]  += qv * b1;
    sim[10] += qv * a2.x; sim[11] += qv * a2.y; sim[12] += qv * a2.z;
    sim[13] += qv * a2.w; sim[14] += qv * b2;
    sim[15] += qv * a3.x; sim[16] += qv * a3.y; sim[17] += qv * a3.z;
    sim[18] += qv * a3.w; sim[19] += qv * b3;
    sim[20] += qv * a4.x; sim[21] += qv * a4.y; sim[22] += qv * a4.z;
    sim[23] += qv * a4.w; sim[24] += qv * b4;

    // gating conv taps (3x3) from already-loaded registers
    const float q3[9] = {q0.x, q0.y, q0.z, q1.x, q1.y, q1.z, q2.x, q2.y, q2.z};
    const float k3[9] = {a1.y, a1.z, a1.w, a2.y, a2.z, a2.w, a3.y, a3.z, a3.w};
    const int c = cgu * 16 + ci;                 // scalar -> s_load weights
    const float* w0q = wa + c * 9;
    const float* w1q = wa + 2304 + c * 9;
    const float* w0k = wa + (C + c) * 9;
    const float* w1k = wa + 2304 + (C + c) * 9;
#pragma unroll
    for (int tp = 0; tp < 9; tp++) {
      d0a += w0q[tp] * q3[tp] + w0k[tp] * k3[tp];
      d1a += w1q[tp] * q3[tp] + w1k[tp] * k3[tp];
    }
  }

  // stash partials
#pragma unroll
  for (int k = 0; k < 25; k++) red[k * 512 + tid] = sim[k];
  dsh[tid] = d0a;
  dsh[512 + tid] = d1a;
  __syncthreads();

  // reduce over the 8 waves; slots 25,26 carry the gating sums
  for (int k = cgu; k < 27; k += 8) {
    if (k < 25) {
      float s = 0.f;
#pragma unroll
      for (int g = 0; g < 8; g++) s += red[k * 512 + g * 64 + px];
      red[k * 512 + px] = s;
    } else if (k == 25) {
      float s = 0.f;
#pragma unroll
      for (int g = 0; g < 8; g++) s += dsh[g * 64 + px];
      dsh[px] = s;
    } else {
      float s = 0.f;
#pragma unroll
      for (int g = 0; g < 8; g++) s += dsh[512 + g * 64 + px];
      dsh[512 + px] = s;
    }
  }
  __syncthreads();

  // softmax + sigmoid (threads 0..63; OOB taps have sim == 0 as in reference)
  if (tid < 64) {
    float sv[25], m = -1e30f;
#pragma unroll
    for (int k = 0; k < 25; k++) { sv[k] = red[k * 512 + tid]; m = fmaxf(m, sv[k]); }
    float tot = 0.f;
#pragma unroll
    for (int k = 0; k < 25; k++) { const float e = expf(sv[k] - m); sv[k] = e; tot += e; }
    const float inv = 1.f / tot;
#pragma unroll
    for (int k = 0; k < 25; k++) red[k * 512 + tid] = sv[k] * inv;
    dsh[tid] = 1.f / (1.f + expf(-(dsh[tid] + ba[0])));
    dsh[512 + tid] = 1.f / (1.f + expf(-(dsh[512 + tid] + ba[1])));
  }
  __syncthreads();

  float w[25];
#pragma unroll
  for (int k = 0; k < 25; k++) w[k] = red[k * 512 + px];
  const float g0 = dsh[px], g1 = dsh[512 + px];

  // value pass + epilogue
  const float* vb = vpad + c0 * KPLANE + y * KRW + x;
  float* op = outb + c0 * HW + y * Wd + x;
#pragma unroll 4
  for (int ci = 0; ci < 16; ci++) {
    const float* vp = vb + ci * KPLANE;
    const f4u a0 = *(const f4u*)(vp);
    const f4u a1 = *(const f4u*)(vp + KRW);
    const f4u a2 = *(const f4u*)(vp + 2 * KRW);
    const f4u a3 = *(const f4u*)(vp + 3 * KRW);
    const f4u a4 = *(const f4u*)(vp + 4 * KRW);
    const float b0 = vp[4];
    const float b1 = vp[KRW + 4];
    const float b2 = vp[2 * KRW + 4];
    const float b3 = vp[3 * KRW + 4];
    const float b4 = vp[4 * KRW + 4];

    float acc;
    acc  = w[0]  * a0.x + w[1]  * a0.y + w[2]  * a0.z + w[3]  * a0.w + w[4]  * b0;
    acc += w[5]  * a1.x + w[6]  * a1.y + w[7]  * a1.z + w[8]  * a1.w + w[9]  * b1;
    acc += w[10] * a2.x + w[11] * a2.y + w[12] * a2.z + w[13] * a2.w + w[14] * b2;
    acc += w[15] * a3.x + w[16] * a3.y + w[17] * a3.z + w[18] * a3.w + w[19] * b3;
    acc += w[20] * a4.x + w[21] * a4.y + w[22] * a4.z + w[23] * a4.w + w[24] * b4;
    const float vc = a2.z;                       // center tap (dy=0,dx=0)
    op[ci * HW] = op[ci * HW] + g0 * acc + g1 * vc;   // op holds lr_up
  }
}

// ---------------------------------------------------------------------------
extern "C" void kernel_launch(void* const* d_in, const int* in_sizes, int n_in,
                              void* d_out, int out_size, void* d_ws,
                              size_t ws_size, hipStream_t stream)
{
  const float* hr = (const float*)d_in[0];
  const float* lr = (const float*)d_in[1];
  const float* wq = (const float*)d_in[2];
  const float* bq = (const float*)d_in[3];
  const float* wk = (const float*)d_in[4];
  const float* bk = (const float*)d_in[5];
  const float* wv = (const float*)d_in[6];
  const float* bv = (const float*)d_in[7];
  const float* wa = (const float*)d_in[8];
  const float* ba = (const float*)d_in[9];

  float* out = (float*)d_out;
  float* ws  = (float*)d_ws;

  // layout: kpad | vpad | qpad | gap(4)  = 52.32 MB
  // (k bottom-row spill reads land in vpad's zero top pad, v's in qpad's,
  //  qpad's in the zeroed gap)
  float* kpad = ws;
  float* vpad = kpad + KSZ;
  float* qpad = vpad + KSZ;
  float* gapb = qpad + QSZ;

  k_pre<<<dim3(4096), dim3(256), 0, stream>>>(
      hr, lr, wq, bq, wk, bk, wv, bv, out, qpad, kpad, vpad, gapb);
  k_attn<<<dim3(2, 128, 2), dim3(512), 0, stream>>>(
      qpad, kpad, vpad, wa, ba, out);
}